// Round 10
// baseline (905.922 us; speedup 1.0000x reference)
//
#include <hip/hip_runtime.h>
#include <cstdint>
#include <cstddef>

typedef unsigned short u16;

#define HH 256
#define IIN 128
#define TT 512
#define G3 768
#define RSTR 776    // ring row stride in u16 (768 + 8 pad: spreads row banks)

typedef __attribute__((ext_vector_type(8))) short bf16x8;
typedef __attribute__((ext_vector_type(4))) float f32x4;
typedef __attribute__((ext_vector_type(4))) int   i32x4;

__device__ __forceinline__ u16 f2bf(float f) {
    union { float f; uint32_t i; } c; c.f = f;
    uint32_t r = c.i + 0x7fffu + ((c.i >> 16) & 1u);
    return (u16)(r >> 16);
}
__device__ __forceinline__ float bf2f(u16 s) {
    union { uint32_t i; float f; } u; u.i = ((uint32_t)s) << 16; return u.f;
}
__device__ __forceinline__ float frcp(float x) { return __builtin_amdgcn_rcpf(x); }
__device__ __forceinline__ float sigm(float x) {
    float e = __expf(-fabsf(x));
    float s = frcp(1.f + e);
    return x >= 0.f ? s : 1.f - s;   // 1-s == e/(1+e)
}
__device__ __forceinline__ float tanh_f(float x) {
    float e = __expf(-2.f * fabsf(x));          // overflow-safe
    float t = (1.f - e) * frcp(1.f + e);
    return x >= 0.f ? t : -t;
}

// lgkmcnt-only barrier: drains LDS ops for cross-wave visibility but leaves
// global (vmcnt) loads/stores in flight.
#define LDS_BARRIER() asm volatile("s_waitcnt lgkmcnt(0)\n\ts_barrier" ::: "memory")

// ---------------------------------------------------------------------------
// FULLY-FUSED kernel, xg-in-LDS-ring edition, v2 (spill-free bursts).
// grid=256 (block b = batch b), block=512 (8 waves, 2/SIMD).
//
// R9 post-mortem: persistent Bi[6][4] (96 VGPR) + Bq (96) + burst working
// set blew the 256-reg budget -> ~150 MB spill stores / ~200 MB reloads in
// the hot loop (WRITE 285 MB, FETCH 385 MB), dur 500->669us. The ring math
// itself was verified bitwise (absmax unchanged).
//
// v2: W_ih is STREAMED from L2 inside each burst (one 16-col group at a
// time: 8 float4 loads -> cvt -> 4 MFMAs -> ring store). W_ih (393 KB) is
// L2-resident per XCD; 12.6 MB/block of L2 reads amortized over 16 steps
// per burst. Peak regs ~190 (steady ~130) -> no spills. Recurrence and ring
// indexing byte-identical to R9 -> absmax stays exactly 0.01293945.
// ---------------------------------------------------------------------------
#define GRU_STEP(TC_, HQR_, HQW_) do {                                         \
    const u16* rg_ = &ring[((TC_) >> 4) & 1][(TC_) & 15][0];                   \
    float xr = bf2f(rg_[j]);                                                   \
    float xz = bf2f(rg_[256 + j]);                                             \
    float xn = bf2f(rg_[512 + j]);                                             \
    i32x4 Cr[2] = {}, Cz[2] = {}, Cn[2] = {};                                  \
    _Pragma("unroll")                                                          \
    for (int kt = 0; kt < 4; ++kt) {                                           \
        i32x4 Aq = *(const i32x4*)((const char*)(HQR_) + kt * 64 + quad * 16); \
        Cr[0] = __builtin_amdgcn_mfma_i32_16x16x64_i8(Aq, Bq[0][0][kt], Cr[0], 0, 0, 0); \
        Cr[1] = __builtin_amdgcn_mfma_i32_16x16x64_i8(Aq, Bq[0][1][kt], Cr[1], 0, 0, 0); \
        Cz[0] = __builtin_amdgcn_mfma_i32_16x16x64_i8(Aq, Bq[1][0][kt], Cz[0], 0, 0, 0); \
        Cz[1] = __builtin_amdgcn_mfma_i32_16x16x64_i8(Aq, Bq[1][1][kt], Cz[1], 0, 0, 0); \
        Cn[0] = __builtin_amdgcn_mfma_i32_16x16x64_i8(Aq, Bq[2][0][kt], Cn[0], 0, 0, 0); \
        Cn[1] = __builtin_amdgcn_mfma_i32_16x16x64_i8(Aq, Bq[2][1][kt], Cn[1], 0, 0, 0); \
    }                                                                          \
    float dr = (float)(i16 ? Cr[1][0] : Cr[0][0]) * scG[0];                    \
    float dz = (float)(i16 ? Cz[1][0] : Cz[0][0]) * scG[1];                    \
    float dn = (float)(i16 ? Cn[1][0] : Cn[0][0]) * scG[2];                    \
    float r = sigm(xr + dr);                                                   \
    float z = sigm(xz + dz);                                                   \
    float n = tanh_f(xn + r * (dn + bhn));                                     \
    hreg = n + z * (hreg - n);                                                 \
    float hc = fminf(fmaxf(hreg, -1.f), 1.f);   /* |h|<=1 mathematically */    \
    int hq8 = (int)rintf(hc * 127.f);                                          \
    if (lane < 32) {                                                           \
        ((char*)(HQW_))[j] = (char)hq8;                                        \
        outb[(size_t)(TC_) * HH + j] = hreg;                                   \
    }                                                                          \
    LDS_BARRIER();                                                             \
} while (0)

// produce xg rows tb..tb+15 into ring[HALF_] (tb multiple of 16).
// W_ih is streamed per 16-col group (L2-warm) -- nothing persists in regs.
#define XG_BURST(TB_, HALF_) do {                                              \
    const float* xrow_ = x + ((size_t)b * TT + (TB_) + colL) * IIN;            \
    bf16x8 bA[4];                                                              \
    _Pragma("unroll")                                                          \
    for (int kt = 0; kt < 4; ++kt) {                                           \
        float4 lo = *(const float4*)(xrow_ + kt * 32 + quad * 8);              \
        float4 hi = *(const float4*)(xrow_ + kt * 32 + quad * 8 + 4);          \
        union { bf16x8 v; u16 s[8]; } u_;                                      \
        u_.s[0] = f2bf(lo.x); u_.s[1] = f2bf(lo.y);                            \
        u_.s[2] = f2bf(lo.z); u_.s[3] = f2bf(lo.w);                            \
        u_.s[4] = f2bf(hi.x); u_.s[5] = f2bf(hi.y);                            \
        u_.s[6] = f2bf(hi.z); u_.s[7] = f2bf(hi.w);                            \
        bA[kt] = u_.v;                                                         \
    }                                                                          \
    _Pragma("unroll")                                                          \
    for (int n = 0; n < 6; ++n) {                                              \
        int col_ = wv * 96 + n * 16 + colL;                                    \
        const float* wr_ = W_ih + (size_t)col_ * IIN;                          \
        bf16x8 bB[4];                                                          \
        _Pragma("unroll")                                                      \
        for (int kt = 0; kt < 4; ++kt) {                                       \
            float4 lo = *(const float4*)(wr_ + kt * 32 + quad * 8);            \
            float4 hi = *(const float4*)(wr_ + kt * 32 + quad * 8 + 4);        \
            union { bf16x8 v; u16 s[8]; } u_;                                  \
            u_.s[0] = f2bf(lo.x); u_.s[1] = f2bf(lo.y);                        \
            u_.s[2] = f2bf(lo.z); u_.s[3] = f2bf(lo.w);                        \
            u_.s[4] = f2bf(hi.x); u_.s[5] = f2bf(hi.y);                        \
            u_.s[6] = f2bf(hi.z); u_.s[7] = f2bf(hi.w);                        \
            bB[kt] = u_.v;                                                     \
        }                                                                      \
        f32x4 C = {};                                                          \
        _Pragma("unroll")                                                      \
        for (int kt = 0; kt < 4; ++kt)                                         \
            C = __builtin_amdgcn_mfma_f32_16x16x32_bf16(bA[kt], bB[kt], C, 0, 0, 0); \
        /* C layout [m89]: row = quad*4 + reg, col = lane&15 */                \
        _Pragma("unroll")                                                      \
        for (int r = 0; r < 4; ++r)                                            \
            ring[HALF_][quad * 4 + r][col_] = f2bf(C[r] + bvv[n]);             \
    }                                                                          \
} while (0)

__global__ __launch_bounds__(512, 1) void gru_fused(
    const float* __restrict__ x, const float* __restrict__ W_ih,
    const float* __restrict__ W_hh,
    const float* __restrict__ b_ih, const float* __restrict__ b_hh,
    float* __restrict__ out)
{
    __shared__ u16 ring[2][16][RSTR];              // xg ring: 49,664 B
    __shared__ __align__(16) int hqBuf[2][HH / 4]; // h int8 (*127), dbuf

    const int tid = threadIdx.x;
    const int lane = tid & 63, wv = tid >> 6;       // wv in [0,8)
    const int quad = lane >> 4, colL = lane & 15;
    const int i16 = quad & 1;                       // which 16-col tile
    const int j = wv * 32 + (lane & 31);            // hidden index this lane owns
    const int b = blockIdx.x;

    // ---- per-wave xg bias (6 values); W_ih itself is streamed per burst ----
    float bvv[6];
    #pragma unroll
    for (int n = 0; n < 6; ++n) {
        int col = wv * 96 + n * 16 + colL;
        float bv = b_ih[col];
        if (col < 512) bv += b_hh[col];     // fold b_hh into r,z pre-acts
        bvv[n] = bv;
    }

    // ---- W_hh -> per-row-scaled int8, packed 16 bytes/frag ----
    i32x4 Bq[3][2][4];
    float scG[3] = { 0.f, 0.f, 0.f };   // combined dequant rowmax/(127*127)
    #pragma unroll
    for (int g = 0; g < 3; ++g) {
        #pragma unroll
        for (int i = 0; i < 2; ++i) {
            const float* wr = W_hh + (size_t)(g * 256 + wv * 32 + i * 16 + colL) * HH;
            float m = 0.f;
            #pragma unroll
            for (int kt = 0; kt < 4; ++kt)
                #pragma unroll
                for (int u4 = 0; u4 < 4; ++u4) {
                    float4 v = *(const float4*)(wr + kt * 64 + quad * 16 + u4 * 4);
                    m = fmaxf(m, fmaxf(fmaxf(fabsf(v.x), fabsf(v.y)),
                                       fmaxf(fabsf(v.z), fabsf(v.w))));
                }
            m = fmaxf(m, __shfl_xor(m, 16));    // full row spans all 4 quads
            m = fmaxf(m, __shfl_xor(m, 32));
            float inv = m > 1e-30f ? 127.f / m : 0.f;
            float sc  = m * (1.f / 16129.f);
            #pragma unroll
            for (int kt = 0; kt < 4; ++kt) {
                int pk[4];
                #pragma unroll
                for (int u4 = 0; u4 < 4; ++u4) {
                    float4 v = *(const float4*)(wr + kt * 64 + quad * 16 + u4 * 4);
                    int q0 = (int)rintf(fminf(fmaxf(v.x * inv, -127.f), 127.f));
                    int q1 = (int)rintf(fminf(fmaxf(v.y * inv, -127.f), 127.f));
                    int q2 = (int)rintf(fminf(fmaxf(v.z * inv, -127.f), 127.f));
                    int q3 = (int)rintf(fminf(fmaxf(v.w * inv, -127.f), 127.f));
                    pk[u4] = (q0 & 255) | ((q1 & 255) << 8) | ((q2 & 255) << 16) | (q3 << 24);
                }
                i32x4 t = { pk[0], pk[1], pk[2], pk[3] };
                Bq[g][i][kt] = t;
            }
            if (i == i16) scG[g] = sc;
        }
    }

    float* outb = out + (size_t)b * TT * HH;
    const float bhn = b_hh[512 + j];
    float hreg = 0.f;                       // h0 == 0 (single chunk, T=512)

    // ---- prologue: xg rows 0..15 -> ring half 0; hq(0) = 0 ----
    XG_BURST(0, 0);
    if (tid < 64) hqBuf[0][tid] = 0;
    __syncthreads();

    for (int tc = 0; tc < TT; tc += 2) {
        GRU_STEP(tc, hqBuf[0], hqBuf[1]);
        if (((tc & 15) == 0) && (tc + 16 < TT)) {
            // produce rows tc+16..tc+31 into the half NOT being read this
            // 16-group; visible to readers via the >=15 intervening barriers.
            XG_BURST(tc + 16, ((tc >> 4) + 1) & 1);
        }
        GRU_STEP(tc + 1, hqBuf[1], hqBuf[0]);
    }
}

extern "C" void kernel_launch(void* const* d_in, const int* in_sizes, int n_in,
                              void* d_out, int out_size, void* d_ws, size_t ws_size,
                              hipStream_t stream) {
    const float* x    = (const float*)d_in[0];
    const float* W_ih = (const float*)d_in[1];
    const float* W_hh = (const float*)d_in[2];
    const float* b_ih = (const float*)d_in[3];
    const float* b_hh = (const float*)d_in[4];
    float* out = (float*)d_out;                    // fp32 output [B,T,H]
    (void)d_ws; (void)ws_size;                     // xg never leaves LDS now

    gru_fused<<<dim3(256), 512, 0, stream>>>(
        x, W_ih, W_hh, b_ih, b_hh, out);
}

// Round 11
// 623.123 us; speedup vs baseline: 1.4538x; 1.4538x over previous
//
#include <hip/hip_runtime.h>
#include <cstdint>
#include <cstddef>

typedef unsigned short u16;

#define HH 256
#define IIN 128
#define TT 512
#define G3 768

typedef __attribute__((ext_vector_type(8))) short bf16x8;
typedef __attribute__((ext_vector_type(4))) float f32x4;
typedef __attribute__((ext_vector_type(4))) int   i32x4;

__device__ __forceinline__ u16 f2bf(float f) {
    union { float f; uint32_t i; } c; c.f = f;
    uint32_t r = c.i + 0x7fffu + ((c.i >> 16) & 1u);
    return (u16)(r >> 16);
}
__device__ __forceinline__ float bf2f(u16 s) {
    union { uint32_t i; float f; } u; u.i = ((uint32_t)s) << 16; return u.f;
}
__device__ __forceinline__ float frcp(float x) { return __builtin_amdgcn_rcpf(x); }
__device__ __forceinline__ float sigm(float x) {
    float e = __expf(-fabsf(x));
    float s = frcp(1.f + e);
    return x >= 0.f ? s : 1.f - s;   // 1-s == e/(1+e)
}
__device__ __forceinline__ float tanh_f(float x) {
    float e = __expf(-2.f * fabsf(x));          // overflow-safe
    float t = (1.f - e) * frcp(1.f + e);
    return x >= 0.f ? t : -t;
}

// lgkmcnt-only barrier: drains LDS ops for cross-wave visibility but leaves
// global (vmcnt) loads in flight.
#define LDS_BARRIER() asm volatile("s_waitcnt lgkmcnt(0)\n\ts_barrier" ::: "memory")

// ---------------------------------------------------------------------------
// FUSED kernel, R8 structure + 4 waves/SIMD. grid=256 (block b = batch b),
// block=1024 (16 waves).
//
// R9/R10 post-mortem: the LDS-ring burst serializes into the per-step
// barrier (lgkmcnt(0) drains burst ds_writes -> burst chain on critical
// path): 500 -> 669/825us. REVERTED to R8's bulk phase 1 (68us, traffic
// floor, no barriers).
//
// R11 change: phase-2 step was 2025 cyc vs 979 MFMA floor; the ~1050 tail
// (ds_read latency + 4-deep MFMA chains + sigm/tanh transcendental chain +
// barrier) was exposed at 2 waves/SIMD. Now 16 waves x 16-col slices:
//   - 4 waves/SIMD -> 4-way overlap of the serial tail
//   - per-wave regs: Bq 48 + C 12 + Aq 16 + misc ~= 95 < 128 cap (no spill)
//   - wave owns exactly one 16-col tile per gate -> extract needs no select
// Same accumulation order everywhere -> bitwise-identical output
// (absmax must stay exactly 0.01293945).
// ---------------------------------------------------------------------------
#define GRU_STEP(TC_, HQR_, HQW_, PR_, PZ_, PN_) do {                          \
    i32x4 Cr = {}, Cz = {}, Cn = {};                                           \
    _Pragma("unroll")                                                          \
    for (int kt = 0; kt < 4; ++kt) {                                           \
        i32x4 Aq = *(const i32x4*)((const char*)(HQR_) + kt * 64 + quad * 16); \
        Cr = __builtin_amdgcn_mfma_i32_16x16x64_i8(Aq, Bq[0][kt], Cr, 0, 0, 0); \
        Cz = __builtin_amdgcn_mfma_i32_16x16x64_i8(Aq, Bq[1][kt], Cz, 0, 0, 0); \
        Cn = __builtin_amdgcn_mfma_i32_16x16x64_i8(Aq, Bq[2][kt], Cn, 0, 0, 0); \
    }                                                                          \
    float dr = (float)Cr[0] * scG[0];                                          \
    float dz = (float)Cz[0] * scG[1];                                          \
    float dn = (float)Cn[0] * scG[2];                                          \
    float xr = PR_, xz = PZ_, xn = PN_;                                        \
    int t2 = (TC_) + 2; if (t2 > Tc - 1) t2 = Tc - 1;                          \
    const u16* p2 = xgb + (size_t)t2 * G3;                                     \
    PR_ = bf2f(p2[j]); PZ_ = bf2f(p2[256 + j]); PN_ = bf2f(p2[512 + j]);       \
    float r = sigm(xr + dr);                                                   \
    float z = sigm(xz + dz);                                                   \
    float n = tanh_f(xn + r * (dn + bhn));                                     \
    hreg = n + z * (hreg - n);                                                 \
    float hc = fminf(fmaxf(hreg, -1.f), 1.f);   /* |h|<=1 mathematically */    \
    int hq8 = (int)rintf(hc * 127.f);                                          \
    if (lane < 16) {                                                           \
        ((char*)(HQW_))[j] = (char)hq8;                                        \
        outb[(size_t)(t0 + (TC_)) * HH + j] = hreg;                            \
    }                                                                          \
    LDS_BARRIER();                                                             \
} while (0)

__global__ __launch_bounds__(1024, 1) void gru_fused(
    const float* __restrict__ x, const float* __restrict__ W_ih,
    const float* __restrict__ W_hh,
    const float* __restrict__ b_ih, const float* __restrict__ b_hh,
    u16* __restrict__ xg, float* __restrict__ out,
    float* __restrict__ hstate, int t0, int Tc)
{
    // phase 1: x[b] bf16, stride 136 u16 (272B, odd multiple of 16B ->
    // conflict-free b128 reads). 512*136*2 = 139264 B.
    __shared__ u16 xS[TT * 136];
    // phase 2: h int8 (*127), double-buffered. Only cross-wave state.
    __shared__ __align__(16) int hqBuf[2][HH / 4];

    const int tid = threadIdx.x;
    const int lane = tid & 63, wv = tid >> 6;       // wv in [0,16)
    const int quad = lane >> 4, colL = lane & 15;
    const int j = wv * 16 + colL;                   // hidden index (phase 2)
    const int b = blockIdx.x;

    u16* xgw = xg + (size_t)b * Tc * G3;

    // =========================== phase 1: xg ================================
    {
        // stage x[b] rows [t0, t0+Tc) -> bf16 LDS (coalesced float4)
        for (int idx = tid; idx < Tc * 32; idx += 1024) {
            int r = idx >> 5, c4 = (idx & 31) * 4;
            float4 xv = *(const float4*)(x + ((size_t)b * TT + t0 + r) * IIN + c4);
            ushort4 xs = { f2bf(xv.x), f2bf(xv.y), f2bf(xv.z), f2bf(xv.w) };
            *(ushort4*)&xS[r * 136 + c4] = xs;
        }
        // W_ih -> per-wave register B-frags: wave owns cols [wv*48, wv*48+48)
        bf16x8 Bi[3][4];
        float bvv[3];
        #pragma unroll
        for (int n = 0; n < 3; ++n) {
            int col = wv * 48 + n * 16 + colL;
            const float* wr = W_ih + (size_t)col * IIN;
            #pragma unroll
            for (int kt = 0; kt < 4; ++kt) {
                float4 lo = *(const float4*)(wr + kt * 32 + quad * 8);
                float4 hi = *(const float4*)(wr + kt * 32 + quad * 8 + 4);
                union { bf16x8 v; u16 s[8]; } u;
                u.s[0] = f2bf(lo.x); u.s[1] = f2bf(lo.y);
                u.s[2] = f2bf(lo.z); u.s[3] = f2bf(lo.w);
                u.s[4] = f2bf(hi.x); u.s[5] = f2bf(hi.y);
                u.s[6] = f2bf(hi.z); u.s[7] = f2bf(hi.w);
                Bi[n][kt] = u.v;
            }
            float bv = b_ih[col];
            if (col < 512) bv += b_hh[col];     // fold b_hh into r,z pre-acts
            bvv[n] = bv;
        }
        __syncthreads();                        // xS ready

        // every wave sweeps ALL M-tiles for its 48 cols; no barriers
        for (int mt = 0; mt < Tc / 16; ++mt) {
            bf16x8 A[4];
            #pragma unroll
            for (int kt = 0; kt < 4; ++kt)
                A[kt] = *(const bf16x8*)&xS[(mt * 16 + colL) * 136 + kt * 32 + quad * 8];
            f32x4 C[3] = {};
            #pragma unroll
            for (int kt = 0; kt < 4; ++kt)
                #pragma unroll
                for (int n = 0; n < 3; ++n)
                    C[n] = __builtin_amdgcn_mfma_f32_16x16x32_bf16(A[kt], Bi[n][kt], C[n], 0, 0, 0);
            // C layout [m89]: row = quad*4 + reg, col = lane&15
            #pragma unroll
            for (int n = 0; n < 3; ++n) {
                int col = wv * 48 + n * 16 + colL;
                #pragma unroll
                for (int r = 0; r < 4; ++r) {
                    int tt = mt * 16 + quad * 4 + r;
                    xgw[(size_t)tt * G3 + col] = f2bf(C[n][r] + bvv[n]);
                }
            }
        }
        // all xg stores to L2 before any wave's phase-2 reads
        asm volatile("s_waitcnt vmcnt(0)" ::: "memory");
        __syncthreads();
    }

    // ========================= phase 2: recurrence ==========================
    // wave owns hidden cols [wv*16, wv*16+16) for ALL 3 gates:
    // per-row-scaled int8 weights, packed 16 bytes/frag.
    i32x4 Bq[3][4];
    float scG[3];
    #pragma unroll
    for (int g = 0; g < 3; ++g) {
        const float* wr = W_hh + (size_t)(g * 256 + wv * 16 + colL) * HH;
        float m = 0.f;
        #pragma unroll
        for (int kt = 0; kt < 4; ++kt)
            #pragma unroll
            for (int u4 = 0; u4 < 4; ++u4) {
                float4 v = *(const float4*)(wr + kt * 64 + quad * 16 + u4 * 4);
                m = fmaxf(m, fmaxf(fmaxf(fabsf(v.x), fabsf(v.y)),
                                   fmaxf(fabsf(v.z), fabsf(v.w))));
            }
        m = fmaxf(m, __shfl_xor(m, 16));    // full row spans all 4 quads
        m = fmaxf(m, __shfl_xor(m, 32));
        float inv = m > 1e-30f ? 127.f / m : 0.f;
        scG[g] = m * (1.f / 16129.f);       // rowmax/(127*127)
        #pragma unroll
        for (int kt = 0; kt < 4; ++kt) {
            int pk[4];
            #pragma unroll
            for (int u4 = 0; u4 < 4; ++u4) {
                float4 v = *(const float4*)(wr + kt * 64 + quad * 16 + u4 * 4);
                int q0 = (int)rintf(fminf(fmaxf(v.x * inv, -127.f), 127.f));
                int q1 = (int)rintf(fminf(fmaxf(v.y * inv, -127.f), 127.f));
                int q2 = (int)rintf(fminf(fmaxf(v.z * inv, -127.f), 127.f));
                int q3 = (int)rintf(fminf(fmaxf(v.w * inv, -127.f), 127.f));
                pk[u4] = (q0 & 255) | ((q1 & 255) << 8) | ((q2 & 255) << 16) | (q3 << 24);
            }
            i32x4 t = { pk[0], pk[1], pk[2], pk[3] };
            Bq[g][kt] = t;
        }
    }

    float hreg = (t0 == 0) ? 0.f : hstate[b * HH + j];
    if (lane < 16) {
        float hc = fminf(fmaxf(hreg, -1.f), 1.f);
        ((char*)hqBuf[0])[j] = (char)(int)rintf(hc * 127.f);
    }
    const float bhn = b_hh[512 + j];
    const u16* xgb = xgw;
    float* outb = out + (size_t)b * TT * HH;

    // 2-deep xg prefetch (lanes >=16 duplicate lane&15 -> same cachelines)
    float pr0 = bf2f(xgb[j]),      pz0 = bf2f(xgb[256 + j]),      pn0 = bf2f(xgb[512 + j]);
    float pr1 = bf2f(xgb[G3 + j]), pz1 = bf2f(xgb[G3 + 256 + j]), pn1 = bf2f(xgb[G3 + 512 + j]);
    __syncthreads();   // once: weight/h init visible

    for (int tc = 0; tc < Tc; tc += 2) {
        GRU_STEP(tc,     hqBuf[0], hqBuf[1], pr0, pz0, pn0);
        GRU_STEP(tc + 1, hqBuf[1], hqBuf[0], pr1, pz1, pn1);
    }

    if (t0 + Tc < TT && lane < 16)      // only needed across chunks
        hstate[b * HH + j] = hreg;
}

extern "C" void kernel_launch(void* const* d_in, const int* in_sizes, int n_in,
                              void* d_out, int out_size, void* d_ws, size_t ws_size,
                              hipStream_t stream) {
    const float* x    = (const float*)d_in[0];
    const float* W_ih = (const float*)d_in[1];
    const float* W_hh = (const float*)d_in[2];
    const float* b_ih = (const float*)d_in[3];
    const float* b_hh = (const float*)d_in[4];
    float* out = (float*)d_out;                    // fp32 output [B,T,H]

    float* hstate = (float*)d_ws;                  // 256*256 fp32 = 256 KB
    u16* xg = (u16*)((char*)d_ws + 262144);        // [256*Tc, 768] bf16
    size_t avail = ws_size > 262144 ? ws_size - 262144 : 0;

    int Tc = TT;                                   // shrink chunk to fit ws
    while (Tc > 16 && (size_t)256 * Tc * G3 * 2 > avail) Tc >>= 1;

    for (int t0 = 0; t0 < TT; t0 += Tc) {
        gru_fused<<<dim3(256), 1024, 0, stream>>>(
            x, W_ih, W_hh, b_ih, b_hh, xg, out, hstate, t0, Tc);
    }
}